// Round 1
// baseline (537.840 us; speedup 1.0000x reference)
//
#include <hip/hip_runtime.h>

typedef unsigned short u16;
typedef __attribute__((ext_vector_type(8))) short short8;
typedef __attribute__((ext_vector_type(4))) float f32x4;

#define A_ 4
#define T_ 128
#define B_ 256
#define OBS_ 128
#define H_ 128
#define G_ 384
#define ACT_ 8

__device__ __forceinline__ u16 f2b(float x) {
    unsigned int u = __float_as_uint(x);
    u = (u + 0x7fffu + ((u >> 16) & 1u)) >> 16;
    return (u16)u;
}
__device__ __forceinline__ float b2f(u16 h) {
    return __uint_as_float(((unsigned int)h) << 16);
}
__device__ __forceinline__ float sigmoidf_(float x) {
    return 1.0f / (1.0f + __expf(-x));
}
__device__ __forceinline__ float tanhf_(float x) {
    return 2.0f / (1.0f + __expf(-2.0f * x)) - 1.0f;
}
__device__ __forceinline__ f32x4 mfma16(short8 a, short8 b, f32x4 c) {
    return __builtin_amdgcn_mfma_f32_16x16x32_bf16(a, b, c, 0, 0, 0);
}

// ---------------- K0: weight transpose/convert + std output ----------------
// per-agent segment sizes (output elems): WeT 16384 | WiT 49152 | WhT 49152 |
// Wa1T 16384 | Wc1T 16384 | h2T 2048   (total 149504/agent)
__global__ void k_prep(const float* __restrict__ We, const float* __restrict__ Wi,
                       const float* __restrict__ Wh, const float* __restrict__ Wa1,
                       const float* __restrict__ Wc1, const float* __restrict__ Wa2,
                       const float* __restrict__ Wc2, const float* __restrict__ log_std,
                       u16* __restrict__ weT, u16* __restrict__ wiT, u16* __restrict__ whT,
                       u16* __restrict__ wa1T, u16* __restrict__ wc1T, u16* __restrict__ h2T,
                       float* __restrict__ std_out) {
    const int PER_A = 149504;
    int idx = blockIdx.x * 256 + threadIdx.x;
    const int total = 4 * PER_A;
    if (idx < total) {
        int a = idx / PER_A;
        int i = idx % PER_A;
        if (i < 16384) {
            int h = i >> 7, o = i & 127;
            weT[a * 16384 + i] = f2b(We[a * 16384 + o * 128 + h]);
        } else if (i < 16384 + 49152) {
            int j = i - 16384; int g = j >> 7, k = j & 127;
            wiT[a * 49152 + j] = f2b(Wi[a * 49152 + k * 384 + g]);
        } else if (i < 16384 + 2 * 49152) {
            int j = i - 16384 - 49152; int g = j >> 7, k = j & 127;
            whT[a * 49152 + j] = f2b(Wh[a * 49152 + k * 384 + g]);
        } else if (i < 2 * 16384 + 2 * 49152) {
            int j = i - 16384 - 2 * 49152; int h2 = j >> 7, k = j & 127;
            wa1T[a * 16384 + j] = f2b(Wa1[a * 16384 + k * 128 + h2]);
        } else if (i < 3 * 16384 + 2 * 49152) {
            int j = i - 2 * 16384 - 2 * 49152; int h2 = j >> 7, k = j & 127;
            wc1T[a * 16384 + j] = f2b(Wc1[a * 16384 + k * 128 + h2]);
        } else {
            int j = i - 3 * 16384 - 2 * 49152; int row = j >> 7, k = j & 127;
            float v = 0.f;
            if (row < 8) v = Wa2[a * 1024 + k * 8 + row];
            else if (row == 8) v = Wc2[a * 128 + k];
            h2T[a * 2048 + j] = f2b(v);
        }
    } else if (idx < total + 32) {
        int i = idx - total;
        std_out[i] = __expf(log_std[i]);
    }
}

// ---------------- K1: fused emb = tanh(obs@We+be); xi = emb@Wi+bi ----------
// wave = one 16-row tile (fixed t, 16 consecutive b). xi written to ws in the
// exact C-frag layout K2 consumes: idx = ((((a*16+bt)*T+t)*4+w)*64+lane)*24+s*4+r
__global__ __launch_bounds__(256) void k_embed_xi(
    const float* __restrict__ obs, const float* __restrict__ be, const float* __restrict__ bi,
    const u16* __restrict__ weT, const u16* __restrict__ wiT, u16* __restrict__ xi_ws) {
    __shared__ __align__(16) u16 elds[4][16][136];
    const int a = blockIdx.y;
    const int wid = threadIdx.x >> 6, lane = threadIdx.x & 63;
    const int tile = blockIdx.x * 4 + wid;          // [0,2048)
    const int t = tile >> 4, btile = tile & 15;
    const int m = lane & 15, quad = lane >> 4;

    // A-frags from fp32 obs (rows = 16 b's, k consecutive)
    short8 aobs[4];
    const float* orow = obs + (((size_t)a * T_ + t) * B_ + btile * 16 + m) * OBS_ + quad * 8;
#pragma unroll
    for (int ks = 0; ks < 4; ++ks) {
        float4 f0 = *(const float4*)(orow + ks * 32);
        float4 f1 = *(const float4*)(orow + ks * 32 + 4);
        short8 v;
        v[0] = (short)f2b(f0.x); v[1] = (short)f2b(f0.y);
        v[2] = (short)f2b(f0.z); v[3] = (short)f2b(f0.w);
        v[4] = (short)f2b(f1.x); v[5] = (short)f2b(f1.y);
        v[6] = (short)f2b(f1.z); v[7] = (short)f2b(f1.w);
        aobs[ks] = v;
    }

    // emb chain
    f32x4 acc8[8];
#pragma unroll
    for (int ct = 0; ct < 8; ++ct) acc8[ct] = f32x4{0.f, 0.f, 0.f, 0.f};
    const u16* weTa = weT + a * 16384;
#pragma unroll
    for (int ks = 0; ks < 4; ++ks)
#pragma unroll
        for (int ct = 0; ct < 8; ++ct) {
            short8 b = *(const short8*)(weTa + (ct * 16 + m) * 128 + ks * 32 + quad * 8);
            acc8[ct] = mfma16(aobs[ks], b, acc8[ct]);
        }
    const float* bea = be + a * H_;
#pragma unroll
    for (int ct = 0; ct < 8; ++ct) {
        int col = ct * 16 + m;
        float bb = bea[col];
#pragma unroll
        for (int r = 0; r < 4; ++r)
            elds[wid][quad * 4 + r][col] = f2b(tanhf_(acc8[ct][r] + bb));
    }
    __syncthreads();
    short8 aemb[4];
#pragma unroll
    for (int ks = 0; ks < 4; ++ks)
        aemb[ks] = *(const short8*)&elds[wid][m][ks * 32 + quad * 8];

    // xi chain
    f32x4 acc24[24];
#pragma unroll
    for (int ct = 0; ct < 24; ++ct) acc24[ct] = f32x4{0.f, 0.f, 0.f, 0.f};
    const u16* wiTa = wiT + a * 49152;
#pragma unroll
    for (int ks = 0; ks < 4; ++ks)
#pragma unroll
        for (int ct = 0; ct < 24; ++ct) {
            short8 b = *(const short8*)(wiTa + (ct * 16 + m) * 128 + ks * 32 + quad * 8);
            acc24[ct] = mfma16(aemb[ks], b, acc24[ct]);
        }
    const float* bia = bi + a * G_;
    const size_t base = ((size_t)(a * 16 + btile) * T_ + t) * 4;
#pragma unroll
    for (int ct = 0; ct < 24; ++ct) {
        int g0 = ct * 16 + m;
        float bb = bia[g0];
        int w2 = (ct & 7) >> 1;                  // K2 wave that consumes this tile
        int s = (ct >> 3) * 2 + (ct & 1);        // slot = gate*2 + cg
        ushort4 pk;
        pk.x = f2b(acc24[ct][0] + bb);
        pk.y = f2b(acc24[ct][1] + bb);
        pk.z = f2b(acc24[ct][2] + bb);
        pk.w = f2b(acc24[ct][3] + bb);
        *(ushort4*)(xi_ws + ((base + w2) * 64 + lane) * 24 + s * 4) = pk;
    }
}

// ---------------- K2: GRU scan, Wh register-resident -----------------------
// grid (16,4): block = (agent, 16-row batch tile); 4 waves split the 384 gate
// columns; h kept fp32 in regs at C-layout positions; bf16 copy -> LDS only as
// MFMA A-operand. xi/done prefetched one step ahead.
__global__ __launch_bounds__(256) void k_scan(
    const float* __restrict__ hstate, const u16* __restrict__ xi_ws,
    const u16* __restrict__ whT, const float* __restrict__ bhn,
    const int* __restrict__ done, u16* __restrict__ ys_ws, float* __restrict__ hT_out) {
    __shared__ __align__(16) u16 hlds[16][136];
    const int a = blockIdx.y, btile = blockIdx.x;
    const int wid = threadIdx.x >> 6, lane = threadIdx.x & 63;
    const int m = lane & 15, quad = lane >> 4;
    const int b0 = btile * 16;

    // resident B-frags: slot s -> gate (s>>1), col-group (s&1); ct = gate*8 + 2*wid + cg
    short8 wh[6][4];
    const u16* whTa = whT + a * 49152;
#pragma unroll
    for (int s = 0; s < 6; ++s) {
        const int ct = (s >> 1) * 8 + 2 * wid + (s & 1);
        const u16* p = whTa + (ct * 16 + m) * 128 + quad * 8;
#pragma unroll
        for (int ks = 0; ks < 4; ++ks) wh[s][ks] = *(const short8*)(p + ks * 32);
    }

    float hm[2][4];
#pragma unroll
    for (int r = 0; r < 4; ++r) {
        const int brow = b0 + quad * 4 + r;
        hm[0][r] = hstate[((size_t)a * B_ + brow) * H_ + 32 * wid + m];
        hm[1][r] = hstate[((size_t)a * B_ + brow) * H_ + 32 * wid + 16 + m];
    }
    const float bh0 = bhn[a * H_ + 32 * wid + m];
    const float bh1 = bhn[a * H_ + 32 * wid + 16 + m];

    const u16* xibase = xi_ws + (((size_t)(a * 16 + btile) * T_) * 4 + wid) * 64 * 24 + lane * 24;
    const int* dbase = done + (size_t)a * T_ * B_ + b0 + quad * 4;

    uint4 pf0 = *(const uint4*)(xibase);
    uint4 pf1 = *(const uint4*)(xibase + 8);
    uint4 pf2 = *(const uint4*)(xibase + 16);
    int dpf0 = dbase[0], dpf1 = dbase[1], dpf2 = dbase[2], dpf3 = dbase[3];

    for (int t = 0; t < T_; ++t) {
        __syncthreads();  // prior step's A-reads done before we overwrite h
        int dmask[4] = {dpf0, dpf1, dpf2, dpf3};
#pragma unroll
        for (int r = 0; r < 4; ++r) {
            if (dmask[r]) { hm[0][r] = 0.f; hm[1][r] = 0.f; }
            const int rr = quad * 4 + r;
            hlds[rr][32 * wid + m] = f2b(hm[0][r]);
            hlds[rr][32 * wid + 16 + m] = f2b(hm[1][r]);
        }
        __syncthreads();

        // consume prefetched xi for step t
        float xv[24];
        {
            union { uint4 q[3]; u16 u[24]; } uu;
            uu.q[0] = pf0; uu.q[1] = pf1; uu.q[2] = pf2;
#pragma unroll
            for (int i = 0; i < 24; ++i) xv[i] = b2f(uu.u[i]);
        }
        // prefetch t+1
        if (t + 1 < T_) {
            const u16* xip = xibase + (size_t)(t + 1) * 6144;
            pf0 = *(const uint4*)(xip);
            pf1 = *(const uint4*)(xip + 8);
            pf2 = *(const uint4*)(xip + 16);
            const int* dp = dbase + (size_t)(t + 1) * B_;
            dpf0 = dp[0]; dpf1 = dp[1]; dpf2 = dp[2]; dpf3 = dp[3];
        }

        short8 af[4];
#pragma unroll
        for (int ks = 0; ks < 4; ++ks)
            af[ks] = *(const short8*)&hlds[m][ks * 32 + quad * 8];

        f32x4 acc[6];
#pragma unroll
        for (int s = 0; s < 6; ++s) acc[s] = f32x4{0.f, 0.f, 0.f, 0.f};
#pragma unroll
        for (int ks = 0; ks < 4; ++ks)
#pragma unroll
            for (int s = 0; s < 6; ++s) acc[s] = mfma16(af[ks], wh[s][ks], acc[s]);

#pragma unroll
        for (int cg = 0; cg < 2; ++cg) {
            const float bh = cg ? bh1 : bh0;
#pragma unroll
            for (int r = 0; r < 4; ++r) {
                const float rg = sigmoidf_(xv[(0 + cg) * 4 + r] + acc[0 + cg][r]);
                const float zg = sigmoidf_(xv[(2 + cg) * 4 + r] + acc[2 + cg][r]);
                const float ng = tanhf_(xv[(4 + cg) * 4 + r] + rg * (acc[4 + cg][r] + bh));
                const float hn = (1.f - zg) * ng + zg * hm[cg][r];
                hm[cg][r] = hn;
                const int brow = b0 + quad * 4 + r;
                ys_ws[(((size_t)a * T_ + t) * B_ + brow) * H_ + 32 * wid + 16 * cg + m] = f2b(hn);
            }
        }
    }
#pragma unroll
    for (int r = 0; r < 4; ++r) {
        const int brow = b0 + quad * 4 + r;
        hT_out[((size_t)a * B_ + brow) * H_ + 32 * wid + m] = hm[0][r];
        hT_out[((size_t)a * B_ + brow) * H_ + 32 * wid + 16 + m] = hm[1][r];
    }
}

// ---------------- K3: actor/critic heads -----------------------------------
__global__ __launch_bounds__(256) void k_heads(
    const u16* __restrict__ ys_ws, const u16* __restrict__ wa1T, const u16* __restrict__ wc1T,
    const u16* __restrict__ h2T, const float* __restrict__ ba1, const float* __restrict__ bc1,
    const float* __restrict__ ba2, const float* __restrict__ bc2,
    float* __restrict__ mean_out, float* __restrict__ val_out) {
    __shared__ __align__(16) u16 alds[4][2][16][136];
    const int a = blockIdx.y;
    const int wid = threadIdx.x >> 6, lane = threadIdx.x & 63;
    const int tile = blockIdx.x * 4 + wid;  // [0,2048) over flattened (t*B+b)/16
    const int m = lane & 15, quad = lane >> 4;

    short8 ay[4];
    const u16* yrow = ys_ws + ((size_t)a * 32768 + tile * 16 + m) * 128 + quad * 8;
#pragma unroll
    for (int ks = 0; ks < 4; ++ks) ay[ks] = *(const short8*)(yrow + ks * 32);

    f32x4 aa[8], ac[8];
#pragma unroll
    for (int ct = 0; ct < 8; ++ct) { aa[ct] = f32x4{0.f, 0.f, 0.f, 0.f}; ac[ct] = f32x4{0.f, 0.f, 0.f, 0.f}; }
    const u16* wa = wa1T + a * 16384;
    const u16* wc = wc1T + a * 16384;
#pragma unroll
    for (int ks = 0; ks < 4; ++ks)
#pragma unroll
        for (int ct = 0; ct < 8; ++ct) {
            short8 b1 = *(const short8*)(wa + (ct * 16 + m) * 128 + ks * 32 + quad * 8);
            aa[ct] = mfma16(ay[ks], b1, aa[ct]);
            short8 b2 = *(const short8*)(wc + (ct * 16 + m) * 128 + ks * 32 + quad * 8);
            ac[ct] = mfma16(ay[ks], b2, ac[ct]);
        }
#pragma unroll
    for (int ct = 0; ct < 8; ++ct) {
        int col = ct * 16 + m;
        float fa = ba1[a * 128 + col];
        float fc = bc1[a * 128 + col];
#pragma unroll
        for (int r = 0; r < 4; ++r) {
            alds[wid][0][quad * 4 + r][col] = f2b(tanhf_(aa[ct][r] + fa));
            alds[wid][1][quad * 4 + r][col] = f2b(tanhf_(ac[ct][r] + fc));
        }
    }
    __syncthreads();
    short8 aya[4], ayc[4];
#pragma unroll
    for (int ks = 0; ks < 4; ++ks) {
        aya[ks] = *(const short8*)&alds[wid][0][m][ks * 32 + quad * 8];
        ayc[ks] = *(const short8*)&alds[wid][1][m][ks * 32 + quad * 8];
    }
    f32x4 am = f32x4{0.f, 0.f, 0.f, 0.f}, av = f32x4{0.f, 0.f, 0.f, 0.f};
    const u16* h2 = h2T + a * 2048;
#pragma unroll
    for (int ks = 0; ks < 4; ++ks) {
        short8 b = *(const short8*)(h2 + m * 128 + ks * 32 + quad * 8);
        am = mfma16(aya[ks], b, am);
        av = mfma16(ayc[ks], b, av);
    }
    const size_t R0 = (size_t)a * 32768 + tile * 16;
    if (m < 8) {
        float bb = ba2[a * 8 + m];
#pragma unroll
        for (int r = 0; r < 4; ++r) mean_out[(R0 + quad * 4 + r) * 8 + m] = am[r] + bb;
    } else if (m == 8) {
        float bb = bc2[a];
#pragma unroll
        for (int r = 0; r < 4; ++r) val_out[R0 + quad * 4 + r] = av[r] + bb;
    }
}

extern "C" void kernel_launch(void* const* d_in, const int* in_sizes, int n_in,
                              void* d_out, int out_size, void* d_ws, size_t ws_size,
                              hipStream_t stream) {
    const float* hstate = (const float*)d_in[0];
    const float* obs = (const float*)d_in[1];
    // d_in[2] = avail_actions (unused by reference)
    const float* We = (const float*)d_in[3];
    const float* be = (const float*)d_in[4];
    const float* Wi = (const float*)d_in[5];
    const float* bi = (const float*)d_in[6];
    const float* Wh = (const float*)d_in[7];
    const float* bhn = (const float*)d_in[8];
    const float* Wa1 = (const float*)d_in[9];
    const float* ba1 = (const float*)d_in[10];
    const float* Wa2 = (const float*)d_in[11];
    const float* ba2 = (const float*)d_in[12];
    const float* log_std = (const float*)d_in[13];
    const float* Wc1 = (const float*)d_in[14];
    const float* bc1 = (const float*)d_in[15];
    const float* Wc2 = (const float*)d_in[16];
    const float* bc2 = (const float*)d_in[17];
    const int* done = (const int*)d_in[18];

    float* out = (float*)d_out;
    float* hT_out = out;                    // (4,256,128)
    float* mean_out = out + 131072;         // (4,128,256,8)
    float* std_out = out + 1179648;         // (4,8)
    float* val_out = out + 1179680;         // (4,128,256)

    // ws layout (u16 elems): xi 50331648 | ys 16777216 | weT 65536 | wiT 196608
    //                        | whT 196608 | wa1T 65536 | wc1T 65536 | h2T 8192
    u16* ws = (u16*)d_ws;
    u16* xi = ws;
    u16* ys = xi + 50331648;
    u16* weT = ys + 16777216;
    u16* wiT = weT + 65536;
    u16* whT = wiT + 196608;
    u16* wa1T = whT + 196608;
    u16* wc1T = wa1T + 65536;
    u16* h2T = wc1T + 65536;

    hipLaunchKernelGGL(k_prep, dim3(2337), dim3(256), 0, stream,
                       We, Wi, Wh, Wa1, Wc1, Wa2, Wc2, log_std,
                       weT, wiT, whT, wa1T, wc1T, h2T, std_out);
    hipLaunchKernelGGL(k_embed_xi, dim3(512, 4), dim3(256), 0, stream,
                       obs, be, bi, weT, wiT, xi);
    hipLaunchKernelGGL(k_scan, dim3(16, 4), dim3(256), 0, stream,
                       hstate, xi, whT, bhn, done, ys, hT_out);
    hipLaunchKernelGGL(k_heads, dim3(512, 4), dim3(256), 0, stream,
                       ys, wa1T, wc1T, h2T, ba1, bc1, ba2, bc2, mean_out, val_out);
}

// Round 2
// 455.026 us; speedup vs baseline: 1.1820x; 1.1820x over previous
//
#include <hip/hip_runtime.h>

typedef unsigned short u16;
typedef __attribute__((ext_vector_type(8))) short short8;
typedef __attribute__((ext_vector_type(4))) float f32x4;

#define A_ 4
#define T_ 128
#define B_ 256
#define OBS_ 128
#define H_ 128
#define G_ 384
#define ACT_ 8

__device__ __forceinline__ u16 f2b(float x) {
    unsigned int u = __float_as_uint(x);
    u = (u + 0x7fffu + ((u >> 16) & 1u)) >> 16;
    return (u16)u;
}
__device__ __forceinline__ u16 f2bc(float x) {  // cheap RN (ties up) for hot loop
    return (u16)((__float_as_uint(x) + 0x8000u) >> 16);
}
__device__ __forceinline__ float b2f(u16 h) {
    return __uint_as_float(((unsigned int)h) << 16);
}
__device__ __forceinline__ float fexp2_(float x) { return __builtin_amdgcn_exp2f(x); }
__device__ __forceinline__ float frcp_(float x) { return __builtin_amdgcn_rcpf(x); }
__device__ __forceinline__ float sigmoidf_(float x) {
    return frcp_(1.0f + fexp2_(-1.4426950408889634f * x));
}
__device__ __forceinline__ float tanhf_(float x) {
    return 1.0f - 2.0f * frcp_(1.0f + fexp2_(2.8853900817779268f * x));
}
__device__ __forceinline__ f32x4 mfma16(short8 a, short8 b, f32x4 c) {
    return __builtin_amdgcn_mfma_f32_16x16x32_bf16(a, b, c, 0, 0, 0);
}

// ---------------- K0: weight transpose/convert + std output ----------------
__global__ void k_prep(const float* __restrict__ We, const float* __restrict__ Wi,
                       const float* __restrict__ Wh, const float* __restrict__ Wa1,
                       const float* __restrict__ Wc1, const float* __restrict__ Wa2,
                       const float* __restrict__ Wc2, const float* __restrict__ log_std,
                       u16* __restrict__ weT, u16* __restrict__ wiT, u16* __restrict__ whT,
                       u16* __restrict__ wa1T, u16* __restrict__ wc1T, u16* __restrict__ h2T,
                       float* __restrict__ std_out) {
    const int PER_A = 149504;
    int idx = blockIdx.x * 256 + threadIdx.x;
    const int total = 4 * PER_A;
    if (idx < total) {
        int a = idx / PER_A;
        int i = idx % PER_A;
        if (i < 16384) {
            int h = i >> 7, o = i & 127;
            weT[a * 16384 + i] = f2b(We[a * 16384 + o * 128 + h]);
        } else if (i < 16384 + 49152) {
            int j = i - 16384; int g = j >> 7, k = j & 127;
            wiT[a * 49152 + j] = f2b(Wi[a * 49152 + k * 384 + g]);
        } else if (i < 16384 + 2 * 49152) {
            int j = i - 16384 - 49152; int g = j >> 7, k = j & 127;
            whT[a * 49152 + j] = f2b(Wh[a * 49152 + k * 384 + g]);
        } else if (i < 2 * 16384 + 2 * 49152) {
            int j = i - 16384 - 2 * 49152; int h2 = j >> 7, k = j & 127;
            wa1T[a * 16384 + j] = f2b(Wa1[a * 16384 + k * 128 + h2]);
        } else if (i < 3 * 16384 + 2 * 49152) {
            int j = i - 2 * 16384 - 2 * 49152; int h2 = j >> 7, k = j & 127;
            wc1T[a * 16384 + j] = f2b(Wc1[a * 16384 + k * 128 + h2]);
        } else {
            int j = i - 3 * 16384 - 2 * 49152; int row = j >> 7, k = j & 127;
            float v = 0.f;
            if (row < 8) v = Wa2[a * 1024 + k * 8 + row];
            else if (row == 8) v = Wc2[a * 128 + k];
            h2T[a * 2048 + j] = f2b(v);
        }
    } else if (idx < total + 32) {
        int i = idx - total;
        std_out[i] = __expf(log_std[i]);
    }
}

// ---------------- K1: fused emb = tanh(obs@We+be); xi = emb@Wi+bi ----------
// xi stored as ushort4 chunks, coalesced: chunk idx =
//   (((a*16+bt)*T + t)*8 + wid2)*3 + gate, then *64 + lane   (wid2 = K2 wave)
__global__ __launch_bounds__(256) void k_embed_xi(
    const float* __restrict__ obs, const float* __restrict__ be, const float* __restrict__ bi,
    const u16* __restrict__ weT, const u16* __restrict__ wiT, u16* __restrict__ xi_ws) {
    __shared__ __align__(16) u16 elds[4][16][136];
    const int a = blockIdx.y;
    const int wid = threadIdx.x >> 6, lane = threadIdx.x & 63;
    const int tile = blockIdx.x * 4 + wid;          // [0,2048)
    const int t = tile >> 4, btile = tile & 15;
    const int m = lane & 15, quad = lane >> 4;

    short8 aobs[4];
    const float* orow = obs + (((size_t)a * T_ + t) * B_ + btile * 16 + m) * OBS_ + quad * 8;
#pragma unroll
    for (int ks = 0; ks < 4; ++ks) {
        float4 f0 = *(const float4*)(orow + ks * 32);
        float4 f1 = *(const float4*)(orow + ks * 32 + 4);
        short8 v;
        v[0] = (short)f2b(f0.x); v[1] = (short)f2b(f0.y);
        v[2] = (short)f2b(f0.z); v[3] = (short)f2b(f0.w);
        v[4] = (short)f2b(f1.x); v[5] = (short)f2b(f1.y);
        v[6] = (short)f2b(f1.z); v[7] = (short)f2b(f1.w);
        aobs[ks] = v;
    }

    f32x4 acc8[8];
#pragma unroll
    for (int ct = 0; ct < 8; ++ct) acc8[ct] = f32x4{0.f, 0.f, 0.f, 0.f};
    const u16* weTa = weT + a * 16384;
#pragma unroll
    for (int ks = 0; ks < 4; ++ks)
#pragma unroll
        for (int ct = 0; ct < 8; ++ct) {
            short8 b = *(const short8*)(weTa + (ct * 16 + m) * 128 + ks * 32 + quad * 8);
            acc8[ct] = mfma16(aobs[ks], b, acc8[ct]);
        }
    const float* bea = be + a * H_;
#pragma unroll
    for (int ct = 0; ct < 8; ++ct) {
        int col = ct * 16 + m;
        float bb = bea[col];
#pragma unroll
        for (int r = 0; r < 4; ++r)
            elds[wid][quad * 4 + r][col] = f2b(tanhf_(acc8[ct][r] + bb));
    }
    __syncthreads();
    short8 aemb[4];
#pragma unroll
    for (int ks = 0; ks < 4; ++ks)
        aemb[ks] = *(const short8*)&elds[wid][m][ks * 32 + quad * 8];

    f32x4 acc24[24];
#pragma unroll
    for (int ct = 0; ct < 24; ++ct) acc24[ct] = f32x4{0.f, 0.f, 0.f, 0.f};
    const u16* wiTa = wiT + a * 49152;
#pragma unroll
    for (int ks = 0; ks < 4; ++ks)
#pragma unroll
        for (int ct = 0; ct < 24; ++ct) {
            short8 b = *(const short8*)(wiTa + (ct * 16 + m) * 128 + ks * 32 + quad * 8);
            acc24[ct] = mfma16(aemb[ks], b, acc24[ct]);
        }
    const float* bia = bi + a * G_;
    ushort4* xi4 = (ushort4*)xi_ws;
    const size_t base = (((size_t)(a * 16 + btile) * T_ + t)) * 1536;  // 24 chunks * 64 lanes
#pragma unroll
    for (int ct = 0; ct < 24; ++ct) {
        int g0 = ct * 16 + m;
        float bb = bia[g0];
        int w2 = ct & 7, g = ct >> 3;
        ushort4 pk;
        pk.x = f2b(acc24[ct][0] + bb);
        pk.y = f2b(acc24[ct][1] + bb);
        pk.z = f2b(acc24[ct][2] + bb);
        pk.w = f2b(acc24[ct][3] + bb);
        xi4[base + (size_t)(w2 * 3 + g) * 64 + lane] = pk;
    }
}

// ---------------- K2: GRU scan, 8 waves/block, Wh register-resident --------
// grid (16,4) x 512 thr. Wave wid owns h-cols [16*wid, 16*wid+16) and the
// r,z,n gate tiles for those cols (12 MFMA/step). h fp32 in regs (C-layout);
// bf16 copy kept in hb[] and round-tripped through double-buffered LDS as the
// MFMA A-operand. One barrier per step. xi/done prefetched one step ahead.
__global__ __launch_bounds__(512) void k_scan(
    const float* __restrict__ hstate, const u16* __restrict__ xi_ws,
    const u16* __restrict__ whT, const float* __restrict__ bhn,
    const int* __restrict__ done, u16* __restrict__ ys_ws, float* __restrict__ hT_out) {
    __shared__ __align__(16) u16 hlds[2][16][136];
    const int a = blockIdx.y, btile = blockIdx.x;
    const int wid = threadIdx.x >> 6, lane = threadIdx.x & 63;
    const int m = lane & 15, quad = lane >> 4;
    const int b0 = btile * 16;
    const int col = 16 * wid + m;

    short8 wh[3][4];
    const u16* whTa = whT + a * 49152;
#pragma unroll
    for (int g = 0; g < 3; ++g) {
        const u16* p = whTa + (g * 128 + col) * 128 + quad * 8;
#pragma unroll
        for (int ks = 0; ks < 4; ++ks) wh[g][ks] = *(const short8*)(p + ks * 32);
    }

    float hm[4]; u16 hb[4];
#pragma unroll
    for (int r = 0; r < 4; ++r) {
        float v = hstate[((size_t)a * B_ + b0 + quad * 4 + r) * H_ + col];
        hm[r] = v; hb[r] = f2b(v);
    }
    const float bh = bhn[a * H_ + col];

    const ushort4* xi4 = (const ushort4*)xi_ws;
    const size_t xibase = ((size_t)(a * 16 + btile) * T_) * 1536 + wid * 192 + lane;
    const int* dbase = done + (size_t)a * T_ * B_ + b0 + quad * 4;

    ushort4 px0 = xi4[xibase], px1 = xi4[xibase + 64], px2 = xi4[xibase + 128];
    int dn0 = dbase[0], dn1 = dbase[1], dn2 = dbase[2], dn3 = dbase[3];

    for (int t = 0; t < T_; ++t) {
        u16 (*hl)[136] = hlds[t & 1];
        int dn[4] = {dn0, dn1, dn2, dn3};
#pragma unroll
        for (int r = 0; r < 4; ++r) {
            if (dn[r]) { hm[r] = 0.f; hb[r] = 0; }
            hl[quad * 4 + r][col] = hb[r];
        }
        __syncthreads();

        float xr[4], xz[4], xn[4];
        xr[0] = b2f(px0.x); xr[1] = b2f(px0.y); xr[2] = b2f(px0.z); xr[3] = b2f(px0.w);
        xz[0] = b2f(px1.x); xz[1] = b2f(px1.y); xz[2] = b2f(px1.z); xz[3] = b2f(px1.w);
        xn[0] = b2f(px2.x); xn[1] = b2f(px2.y); xn[2] = b2f(px2.z); xn[3] = b2f(px2.w);
        if (t + 1 < T_) {
            const size_t nx = xibase + (size_t)(t + 1) * 1536;
            px0 = xi4[nx]; px1 = xi4[nx + 64]; px2 = xi4[nx + 128];
            const int* dp = dbase + (size_t)(t + 1) * B_;
            dn0 = dp[0]; dn1 = dp[1]; dn2 = dp[2]; dn3 = dp[3];
        }

        short8 af[4];
#pragma unroll
        for (int ks = 0; ks < 4; ++ks)
            af[ks] = *(const short8*)&hl[m][ks * 32 + quad * 8];

        f32x4 ar = f32x4{0.f, 0.f, 0.f, 0.f};
        f32x4 az = f32x4{0.f, 0.f, 0.f, 0.f};
        f32x4 an = f32x4{0.f, 0.f, 0.f, 0.f};
#pragma unroll
        for (int ks = 0; ks < 4; ++ks) {
            ar = mfma16(af[ks], wh[0][ks], ar);
            az = mfma16(af[ks], wh[1][ks], az);
            an = mfma16(af[ks], wh[2][ks], an);
        }

#pragma unroll
        for (int r = 0; r < 4; ++r) {
            const float rg = sigmoidf_(xr[r] + ar[r]);
            const float zg = sigmoidf_(xz[r] + az[r]);
            const float ng = tanhf_(fmaf(rg, an[r] + bh, xn[r]));
            const float hn2 = fmaf(zg, hm[r] - ng, ng);
            hm[r] = hn2;
            hb[r] = f2bc(hn2);
            ys_ws[(((size_t)a * T_ + t) * B_ + b0 + quad * 4 + r) * H_ + col] = hb[r];
        }
    }
#pragma unroll
    for (int r = 0; r < 4; ++r)
        hT_out[((size_t)a * B_ + b0 + quad * 4 + r) * H_ + col] = hm[r];
}

// ---------------- K3: actor/critic heads -----------------------------------
__global__ __launch_bounds__(256) void k_heads(
    const u16* __restrict__ ys_ws, const u16* __restrict__ wa1T, const u16* __restrict__ wc1T,
    const u16* __restrict__ h2T, const float* __restrict__ ba1, const float* __restrict__ bc1,
    const float* __restrict__ ba2, const float* __restrict__ bc2,
    float* __restrict__ mean_out, float* __restrict__ val_out) {
    __shared__ __align__(16) u16 alds[4][2][16][136];
    const int a = blockIdx.y;
    const int wid = threadIdx.x >> 6, lane = threadIdx.x & 63;
    const int tile = blockIdx.x * 4 + wid;
    const int m = lane & 15, quad = lane >> 4;

    short8 ay[4];
    const u16* yrow = ys_ws + ((size_t)a * 32768 + tile * 16 + m) * 128 + quad * 8;
#pragma unroll
    for (int ks = 0; ks < 4; ++ks) ay[ks] = *(const short8*)(yrow + ks * 32);

    f32x4 aa[8], ac[8];
#pragma unroll
    for (int ct = 0; ct < 8; ++ct) { aa[ct] = f32x4{0.f, 0.f, 0.f, 0.f}; ac[ct] = f32x4{0.f, 0.f, 0.f, 0.f}; }
    const u16* wa = wa1T + a * 16384;
    const u16* wc = wc1T + a * 16384;
#pragma unroll
    for (int ks = 0; ks < 4; ++ks)
#pragma unroll
        for (int ct = 0; ct < 8; ++ct) {
            short8 b1 = *(const short8*)(wa + (ct * 16 + m) * 128 + ks * 32 + quad * 8);
            aa[ct] = mfma16(ay[ks], b1, aa[ct]);
            short8 b2 = *(const short8*)(wc + (ct * 16 + m) * 128 + ks * 32 + quad * 8);
            ac[ct] = mfma16(ay[ks], b2, ac[ct]);
        }
#pragma unroll
    for (int ct = 0; ct < 8; ++ct) {
        int col = ct * 16 + m;
        float fa = ba1[a * 128 + col];
        float fc = bc1[a * 128 + col];
#pragma unroll
        for (int r = 0; r < 4; ++r) {
            alds[wid][0][quad * 4 + r][col] = f2b(tanhf_(aa[ct][r] + fa));
            alds[wid][1][quad * 4 + r][col] = f2b(tanhf_(ac[ct][r] + fc));
        }
    }
    __syncthreads();
    short8 aya[4], ayc[4];
#pragma unroll
    for (int ks = 0; ks < 4; ++ks) {
        aya[ks] = *(const short8*)&alds[wid][0][m][ks * 32 + quad * 8];
        ayc[ks] = *(const short8*)&alds[wid][1][m][ks * 32 + quad * 8];
    }
    f32x4 am = f32x4{0.f, 0.f, 0.f, 0.f}, av = f32x4{0.f, 0.f, 0.f, 0.f};
    const u16* h2 = h2T + a * 2048;
#pragma unroll
    for (int ks = 0; ks < 4; ++ks) {
        short8 b = *(const short8*)(h2 + m * 128 + ks * 32 + quad * 8);
        am = mfma16(aya[ks], b, am);
        av = mfma16(ayc[ks], b, av);
    }
    const size_t R0 = (size_t)a * 32768 + tile * 16;
    if (m < 8) {
        float bb = ba2[a * 8 + m];
#pragma unroll
        for (int r = 0; r < 4; ++r) mean_out[(R0 + quad * 4 + r) * 8 + m] = am[r] + bb;
    } else if (m == 8) {
        float bb = bc2[a];
#pragma unroll
        for (int r = 0; r < 4; ++r) val_out[R0 + quad * 4 + r] = av[r] + bb;
    }
}

extern "C" void kernel_launch(void* const* d_in, const int* in_sizes, int n_in,
                              void* d_out, int out_size, void* d_ws, size_t ws_size,
                              hipStream_t stream) {
    const float* hstate = (const float*)d_in[0];
    const float* obs = (const float*)d_in[1];
    const float* We = (const float*)d_in[3];
    const float* be = (const float*)d_in[4];
    const float* Wi = (const float*)d_in[5];
    const float* bi = (const float*)d_in[6];
    const float* Wh = (const float*)d_in[7];
    const float* bhn = (const float*)d_in[8];
    const float* Wa1 = (const float*)d_in[9];
    const float* ba1 = (const float*)d_in[10];
    const float* Wa2 = (const float*)d_in[11];
    const float* ba2 = (const float*)d_in[12];
    const float* log_std = (const float*)d_in[13];
    const float* Wc1 = (const float*)d_in[14];
    const float* bc1 = (const float*)d_in[15];
    const float* Wc2 = (const float*)d_in[16];
    const float* bc2 = (const float*)d_in[17];
    const int* done = (const int*)d_in[18];

    float* out = (float*)d_out;
    float* hT_out = out;                    // (4,256,128)
    float* mean_out = out + 131072;         // (4,128,256,8)
    float* std_out = out + 1179648;         // (4,8)
    float* val_out = out + 1179680;         // (4,128,256)

    u16* ws = (u16*)d_ws;
    u16* xi = ws;
    u16* ys = xi + 50331648;
    u16* weT = ys + 16777216;
    u16* wiT = weT + 65536;
    u16* whT = wiT + 196608;
    u16* wa1T = whT + 196608;
    u16* wc1T = wa1T + 65536;
    u16* h2T = wc1T + 65536;

    hipLaunchKernelGGL(k_prep, dim3(2337), dim3(256), 0, stream,
                       We, Wi, Wh, Wa1, Wc1, Wa2, Wc2, log_std,
                       weT, wiT, whT, wa1T, wc1T, h2T, std_out);
    hipLaunchKernelGGL(k_embed_xi, dim3(512, 4), dim3(256), 0, stream,
                       obs, be, bi, weT, wiT, xi);
    hipLaunchKernelGGL(k_scan, dim3(16, 4), dim3(512), 0, stream,
                       hstate, xi, whT, bhn, done, ys, hT_out);
    hipLaunchKernelGGL(k_heads, dim3(512, 4), dim3(256), 0, stream,
                       ys, wa1T, wc1T, h2T, ba1, bc1, ba2, bc2, mean_out, val_out);
}

// Round 3
// 307.410 us; speedup vs baseline: 1.7496x; 1.4802x over previous
//
#include <hip/hip_runtime.h>

typedef unsigned short u16;
typedef __attribute__((ext_vector_type(8))) short short8;
typedef __attribute__((ext_vector_type(4))) float f32x4;

#define A_ 4
#define T_ 128
#define B_ 256
#define OBS_ 128
#define H_ 128
#define G_ 384
#define ACT_ 8

__device__ __forceinline__ u16 f2b(float x) {
    unsigned int u = __float_as_uint(x);
    u = (u + 0x7fffu + ((u >> 16) & 1u)) >> 16;
    return (u16)u;
}
__device__ __forceinline__ u16 f2bc(float x) {  // cheap RN (ties up) for hot loop
    return (u16)((__float_as_uint(x) + 0x8000u) >> 16);
}
__device__ __forceinline__ float b2f(u16 h) {
    return __uint_as_float(((unsigned int)h) << 16);
}
__device__ __forceinline__ float fexp2_(float x) { return __builtin_amdgcn_exp2f(x); }
__device__ __forceinline__ float frcp_(float x) { return __builtin_amdgcn_rcpf(x); }
__device__ __forceinline__ float sigmoidf_(float x) {
    return frcp_(1.0f + fexp2_(-1.4426950408889634f * x));
}
__device__ __forceinline__ float tanhf_(float x) {
    return 1.0f - 2.0f * frcp_(1.0f + fexp2_(2.8853900817779268f * x));
}
__device__ __forceinline__ f32x4 mfma16(short8 a, short8 b, f32x4 c) {
    return __builtin_amdgcn_mfma_f32_16x16x32_bf16(a, b, c, 0, 0, 0);
}

// ---------------- K0: weight transpose/convert + std output ----------------
__global__ void k_prep(const float* __restrict__ We, const float* __restrict__ Wi,
                       const float* __restrict__ Wh, const float* __restrict__ Wa1,
                       const float* __restrict__ Wc1, const float* __restrict__ Wa2,
                       const float* __restrict__ Wc2, const float* __restrict__ log_std,
                       u16* __restrict__ weT, u16* __restrict__ wiT, u16* __restrict__ whT,
                       u16* __restrict__ wa1T, u16* __restrict__ wc1T, u16* __restrict__ h2T,
                       float* __restrict__ std_out) {
    const int PER_A = 149504;
    int idx = blockIdx.x * 256 + threadIdx.x;
    const int total = 4 * PER_A;
    if (idx < total) {
        int a = idx / PER_A;
        int i = idx % PER_A;
        if (i < 16384) {
            int h = i >> 7, o = i & 127;
            weT[a * 16384 + i] = f2b(We[a * 16384 + o * 128 + h]);
        } else if (i < 16384 + 49152) {
            int j = i - 16384; int g = j >> 7, k = j & 127;
            wiT[a * 49152 + j] = f2b(Wi[a * 49152 + k * 384 + g]);
        } else if (i < 16384 + 2 * 49152) {
            int j = i - 16384 - 49152; int g = j >> 7, k = j & 127;
            whT[a * 49152 + j] = f2b(Wh[a * 49152 + k * 384 + g]);
        } else if (i < 2 * 16384 + 2 * 49152) {
            int j = i - 16384 - 2 * 49152; int h2 = j >> 7, k = j & 127;
            wa1T[a * 16384 + j] = f2b(Wa1[a * 16384 + k * 128 + h2]);
        } else if (i < 3 * 16384 + 2 * 49152) {
            int j = i - 2 * 16384 - 2 * 49152; int h2 = j >> 7, k = j & 127;
            wc1T[a * 16384 + j] = f2b(Wc1[a * 16384 + k * 128 + h2]);
        } else {
            int j = i - 3 * 16384 - 2 * 49152; int row = j >> 7, k = j & 127;
            float v = 0.f;
            if (row < 8) v = Wa2[a * 1024 + k * 8 + row];
            else if (row == 8) v = Wc2[a * 128 + k];
            h2T[a * 2048 + j] = f2b(v);
        }
    } else if (idx < total + 32) {
        int i = idx - total;
        std_out[i] = __expf(log_std[i]);
    }
}

// ---------------- K1: fused emb/xi, weight-stationary ----------------------
// grid (128=t, 4=a) x 512 thr. Block loops over the 16 btiles of its t.
// Wave w holds We B-frags for emb cols [16w,16w+16) and Wi B-frags for gate
// cols {g*128 + 16w ..} (g=r,z,n) in registers for the whole kernel.
// Per tile: coalesced obs float4 load -> bf16 LDS; emb (4 MFMA) -> tanh ->
// LDS transpose; xi (12 MFMA) -> coalesced ushort4 stores in K2's layout.
__global__ __launch_bounds__(512) void k_embed_xi(
    const float* __restrict__ obs, const float* __restrict__ be, const float* __restrict__ bi,
    const u16* __restrict__ weT, const u16* __restrict__ wiT, u16* __restrict__ xi_ws) {
    __shared__ __align__(16) u16 obsl[16][136];
    __shared__ __align__(16) u16 elds[16][136];
    const int a = blockIdx.y, t = blockIdx.x;
    const int wid = threadIdx.x >> 6, lane = threadIdx.x & 63;
    const int m = lane & 15, quad = lane >> 4;
    const int srow = threadIdx.x >> 5, schunk = threadIdx.x & 31;

    short8 we[4], wi[3][4];
    {
        const u16* p = weT + a * 16384 + (wid * 16 + m) * 128 + quad * 8;
#pragma unroll
        for (int ks = 0; ks < 4; ++ks) we[ks] = *(const short8*)(p + ks * 32);
#pragma unroll
        for (int g = 0; g < 3; ++g) {
            const u16* q = wiT + a * 49152 + (g * 128 + wid * 16 + m) * 128 + quad * 8;
#pragma unroll
            for (int ks = 0; ks < 4; ++ks) wi[g][ks] = *(const short8*)(q + ks * 32);
        }
    }
    const float bee = be[a * H_ + wid * 16 + m];
    float big[3];
#pragma unroll
    for (int g = 0; g < 3; ++g) big[g] = bi[a * G_ + g * 128 + wid * 16 + m];

    const float* obsrow = obs + ((size_t)(a * T_ + t) * B_ + srow) * OBS_ + schunk * 4;
    float4 pf = *(const float4*)(obsrow);
    ushort4* xi4 = (ushort4*)xi_ws;

    for (int it = 0; it < 16; ++it) {
        ushort4 ob;
        ob.x = f2b(pf.x); ob.y = f2b(pf.y); ob.z = f2b(pf.z); ob.w = f2b(pf.w);
        *(ushort4*)&obsl[srow][schunk * 4] = ob;
        __syncthreads();
        if (it + 1 < 16) pf = *(const float4*)(obsrow + (size_t)(it + 1) * 2048);

        short8 af[4];
#pragma unroll
        for (int ks = 0; ks < 4; ++ks)
            af[ks] = *(const short8*)&obsl[m][ks * 32 + quad * 8];
        f32x4 acc = f32x4{0.f, 0.f, 0.f, 0.f};
#pragma unroll
        for (int ks = 0; ks < 4; ++ks) acc = mfma16(af[ks], we[ks], acc);
#pragma unroll
        for (int r = 0; r < 4; ++r)
            elds[quad * 4 + r][wid * 16 + m] = f2b(tanhf_(acc[r] + bee));
        __syncthreads();

        short8 ef[4];
#pragma unroll
        for (int ks = 0; ks < 4; ++ks)
            ef[ks] = *(const short8*)&elds[m][ks * 32 + quad * 8];
        f32x4 xa[3];
#pragma unroll
        for (int g = 0; g < 3; ++g) xa[g] = f32x4{0.f, 0.f, 0.f, 0.f};
#pragma unroll
        for (int ks = 0; ks < 4; ++ks)
#pragma unroll
            for (int g = 0; g < 3; ++g) xa[g] = mfma16(ef[ks], wi[g][ks], xa[g]);

        const size_t base = ((size_t)(a * 16 + it) * T_ + t) * 1536;
#pragma unroll
        for (int g = 0; g < 3; ++g) {
            ushort4 pk;
            pk.x = f2b(xa[g][0] + big[g]);
            pk.y = f2b(xa[g][1] + big[g]);
            pk.z = f2b(xa[g][2] + big[g]);
            pk.w = f2b(xa[g][3] + big[g]);
            xi4[base + (size_t)(wid * 3 + g) * 64 + lane] = pk;
        }
    }
}

// ---------------- K2: GRU scan, 8 waves/block, Wh register-resident --------
__global__ __launch_bounds__(512) void k_scan(
    const float* __restrict__ hstate, const u16* __restrict__ xi_ws,
    const u16* __restrict__ whT, const float* __restrict__ bhn,
    const int* __restrict__ done, u16* __restrict__ ys_ws, float* __restrict__ hT_out) {
    __shared__ __align__(16) u16 hlds[2][16][136];
    const int a = blockIdx.y, btile = blockIdx.x;
    const int wid = threadIdx.x >> 6, lane = threadIdx.x & 63;
    const int m = lane & 15, quad = lane >> 4;
    const int b0 = btile * 16;
    const int col = 16 * wid + m;

    short8 wh[3][4];
    const u16* whTa = whT + a * 49152;
#pragma unroll
    for (int g = 0; g < 3; ++g) {
        const u16* p = whTa + (g * 128 + col) * 128 + quad * 8;
#pragma unroll
        for (int ks = 0; ks < 4; ++ks) wh[g][ks] = *(const short8*)(p + ks * 32);
    }

    float hm[4]; u16 hb[4];
#pragma unroll
    for (int r = 0; r < 4; ++r) {
        float v = hstate[((size_t)a * B_ + b0 + quad * 4 + r) * H_ + col];
        hm[r] = v; hb[r] = f2b(v);
    }
    const float bh = bhn[a * H_ + col];

    const ushort4* xi4 = (const ushort4*)xi_ws;
    const size_t xibase = ((size_t)(a * 16 + btile) * T_) * 1536 + wid * 192 + lane;
    const int* dbase = done + (size_t)a * T_ * B_ + b0 + quad * 4;

    ushort4 px0 = xi4[xibase], px1 = xi4[xibase + 64], px2 = xi4[xibase + 128];
    int dn0 = dbase[0], dn1 = dbase[1], dn2 = dbase[2], dn3 = dbase[3];

    for (int t = 0; t < T_; ++t) {
        u16 (*hl)[136] = hlds[t & 1];
        int dn[4] = {dn0, dn1, dn2, dn3};
#pragma unroll
        for (int r = 0; r < 4; ++r) {
            if (dn[r]) { hm[r] = 0.f; hb[r] = 0; }
            hl[quad * 4 + r][col] = hb[r];
        }
        __syncthreads();

        float xr[4], xz[4], xn[4];
        xr[0] = b2f(px0.x); xr[1] = b2f(px0.y); xr[2] = b2f(px0.z); xr[3] = b2f(px0.w);
        xz[0] = b2f(px1.x); xz[1] = b2f(px1.y); xz[2] = b2f(px1.z); xz[3] = b2f(px1.w);
        xn[0] = b2f(px2.x); xn[1] = b2f(px2.y); xn[2] = b2f(px2.z); xn[3] = b2f(px2.w);
        if (t + 1 < T_) {
            const size_t nx = xibase + (size_t)(t + 1) * 1536;
            px0 = xi4[nx]; px1 = xi4[nx + 64]; px2 = xi4[nx + 128];
            const int* dp = dbase + (size_t)(t + 1) * B_;
            dn0 = dp[0]; dn1 = dp[1]; dn2 = dp[2]; dn3 = dp[3];
        }

        short8 af[4];
#pragma unroll
        for (int ks = 0; ks < 4; ++ks)
            af[ks] = *(const short8*)&hl[m][ks * 32 + quad * 8];

        f32x4 ar = f32x4{0.f, 0.f, 0.f, 0.f};
        f32x4 az = f32x4{0.f, 0.f, 0.f, 0.f};
        f32x4 an = f32x4{0.f, 0.f, 0.f, 0.f};
#pragma unroll
        for (int ks = 0; ks < 4; ++ks) {
            ar = mfma16(af[ks], wh[0][ks], ar);
            az = mfma16(af[ks], wh[1][ks], az);
            an = mfma16(af[ks], wh[2][ks], an);
        }

#pragma unroll
        for (int r = 0; r < 4; ++r) {
            const float rg = sigmoidf_(xr[r] + ar[r]);
            const float zg = sigmoidf_(xz[r] + az[r]);
            const float ng = tanhf_(fmaf(rg, an[r] + bh, xn[r]));
            const float hn2 = fmaf(zg, hm[r] - ng, ng);
            hm[r] = hn2;
            hb[r] = f2bc(hn2);
            ys_ws[(((size_t)a * T_ + t) * B_ + b0 + quad * 4 + r) * H_ + col] = hb[r];
        }
    }
#pragma unroll
    for (int r = 0; r < 4; ++r)
        hT_out[((size_t)a * B_ + b0 + quad * 4 + r) * H_ + col] = hm[r];
}

// ---------------- K3: actor/critic heads, weight-stationary ----------------
// grid (128, 4) x 512 thr; block loops over 16 row-tiles. Wave w holds Wa1/Wc1
// B-frags for cols [16w,16w+16); all waves hold the stacked (Wa2|Wc2) tile.
// Waves 0/1 do the tiny second GEMM per tile.
__global__ __launch_bounds__(512) void k_heads(
    const u16* __restrict__ ys_ws, const u16* __restrict__ wa1T, const u16* __restrict__ wc1T,
    const u16* __restrict__ h2T, const float* __restrict__ ba1, const float* __restrict__ bc1,
    const float* __restrict__ ba2, const float* __restrict__ bc2,
    float* __restrict__ mean_out, float* __restrict__ val_out) {
    __shared__ __align__(16) u16 ysl[16][136];
    __shared__ __align__(16) u16 al[2][16][136];
    const int a = blockIdx.y;
    const int wid = threadIdx.x >> 6, lane = threadIdx.x & 63;
    const int m = lane & 15, quad = lane >> 4;
    const int srow = threadIdx.x >> 5, schunk = threadIdx.x & 31;

    short8 wa[4], wc[4], h2f[4];
    {
        const u16* pa = wa1T + a * 16384 + (wid * 16 + m) * 128 + quad * 8;
        const u16* pc = wc1T + a * 16384 + (wid * 16 + m) * 128 + quad * 8;
        const u16* ph = h2T + a * 2048 + m * 128 + quad * 8;
#pragma unroll
        for (int ks = 0; ks < 4; ++ks) {
            wa[ks] = *(const short8*)(pa + ks * 32);
            wc[ks] = *(const short8*)(pc + ks * 32);
            h2f[ks] = *(const short8*)(ph + ks * 32);
        }
    }
    const float fa = ba1[a * 128 + wid * 16 + m];
    const float fc = bc1[a * 128 + wid * 16 + m];

    const u16* ysbase = ys_ws + ((size_t)a * 32768 + (size_t)blockIdx.x * 256 + srow) * 128 + schunk * 4;
    ushort4 pf = *(const ushort4*)(ysbase);

    for (int it = 0; it < 16; ++it) {
        *(ushort4*)&ysl[srow][schunk * 4] = pf;
        __syncthreads();
        if (it + 1 < 16) pf = *(const ushort4*)(ysbase + (size_t)(it + 1) * 2048);

        short8 yf[4];
#pragma unroll
        for (int ks = 0; ks < 4; ++ks)
            yf[ks] = *(const short8*)&ysl[m][ks * 32 + quad * 8];
        f32x4 aa = f32x4{0.f, 0.f, 0.f, 0.f};
        f32x4 ac = f32x4{0.f, 0.f, 0.f, 0.f};
#pragma unroll
        for (int ks = 0; ks < 4; ++ks) {
            aa = mfma16(yf[ks], wa[ks], aa);
            ac = mfma16(yf[ks], wc[ks], ac);
        }
#pragma unroll
        for (int r = 0; r < 4; ++r) {
            al[0][quad * 4 + r][wid * 16 + m] = f2b(tanhf_(aa[r] + fa));
            al[1][quad * 4 + r][wid * 16 + m] = f2b(tanhf_(ac[r] + fc));
        }
        __syncthreads();

        if (wid < 2) {
            short8 tf[4];
#pragma unroll
            for (int ks = 0; ks < 4; ++ks)
                tf[ks] = *(const short8*)&al[wid][m][ks * 32 + quad * 8];
            f32x4 tacc = f32x4{0.f, 0.f, 0.f, 0.f};
#pragma unroll
            for (int ks = 0; ks < 4; ++ks) tacc = mfma16(tf[ks], h2f[ks], tacc);
            const size_t R0 = (size_t)a * 32768 + (size_t)(blockIdx.x * 16 + it) * 16;
            if (wid == 0) {
                if (m < 8) {
                    const float bb = ba2[a * 8 + m];
#pragma unroll
                    for (int r = 0; r < 4; ++r)
                        mean_out[(R0 + quad * 4 + r) * 8 + m] = tacc[r] + bb;
                }
            } else {
                if (m == 8) {
                    const float bb = bc2[a];
#pragma unroll
                    for (int r = 0; r < 4; ++r)
                        val_out[R0 + quad * 4 + r] = tacc[r] + bb;
                }
            }
        }
    }
}

extern "C" void kernel_launch(void* const* d_in, const int* in_sizes, int n_in,
                              void* d_out, int out_size, void* d_ws, size_t ws_size,
                              hipStream_t stream) {
    const float* hstate = (const float*)d_in[0];
    const float* obs = (const float*)d_in[1];
    const float* We = (const float*)d_in[3];
    const float* be = (const float*)d_in[4];
    const float* Wi = (const float*)d_in[5];
    const float* bi = (const float*)d_in[6];
    const float* Wh = (const float*)d_in[7];
    const float* bhn = (const float*)d_in[8];
    const float* Wa1 = (const float*)d_in[9];
    const float* ba1 = (const float*)d_in[10];
    const float* Wa2 = (const float*)d_in[11];
    const float* ba2 = (const float*)d_in[12];
    const float* log_std = (const float*)d_in[13];
    const float* Wc1 = (const float*)d_in[14];
    const float* bc1 = (const float*)d_in[15];
    const float* Wc2 = (const float*)d_in[16];
    const float* bc2 = (const float*)d_in[17];
    const int* done = (const int*)d_in[18];

    float* out = (float*)d_out;
    float* hT_out = out;                    // (4,256,128)
    float* mean_out = out + 131072;         // (4,128,256,8)
    float* std_out = out + 1179648;         // (4,8)
    float* val_out = out + 1179680;         // (4,128,256)

    u16* ws = (u16*)d_ws;
    u16* xi = ws;
    u16* ys = xi + 50331648;
    u16* weT = ys + 16777216;
    u16* wiT = weT + 65536;
    u16* whT = wiT + 196608;
    u16* wa1T = whT + 196608;
    u16* wc1T = wa1T + 65536;
    u16* h2T = wc1T + 65536;

    hipLaunchKernelGGL(k_prep, dim3(2337), dim3(256), 0, stream,
                       We, Wi, Wh, Wa1, Wc1, Wa2, Wc2, log_std,
                       weT, wiT, whT, wa1T, wc1T, h2T, std_out);
    hipLaunchKernelGGL(k_embed_xi, dim3(128, 4), dim3(512), 0, stream,
                       obs, be, bi, weT, wiT, xi);
    hipLaunchKernelGGL(k_scan, dim3(16, 4), dim3(512), 0, stream,
                       hstate, xi, whT, bhn, done, ys, hT_out);
    hipLaunchKernelGGL(k_heads, dim3(128, 4), dim3(512), 0, stream,
                       ys, wa1T, wc1T, h2T, ba1, bc1, ba2, bc2, mean_out, val_out);
}